// Round 9
// baseline (200.803 us; speedup 1.0000x reference)
//
#include <hip/hip_runtime.h>
#include <stdint.h>

#define N_NODES 50000
#define N_EDGES 800000
#define D 128
#define CAP 64   // max in-degree supported; Poisson(16) -> P(>=64) ~ 1e-20

typedef __attribute__((ext_vector_type(8))) short short8;
typedef __attribute__((ext_vector_type(4))) float f32x4;
typedef __attribute__((ext_vector_type(4))) unsigned short ush4;

__device__ __forceinline__ unsigned short f2bf(float f) {   // RNE f32->bf16
    uint32_t u = __float_as_uint(f);
    u += 0x7FFFu + ((u >> 16) & 1u);
    return (unsigned short)(u >> 16);
}
__device__ __forceinline__ float bf2f(unsigned short s) {
    return __uint_as_float(((uint32_t)s) << 16);
}

// ---------------------------------------------------------------------------
// convert: x,W1,W2 -> bf16 (vectorized float4->ush4), fused cnt zeroing.
// 6,432,768 floats = 1,608,192 float4.
// ---------------------------------------------------------------------------
#define X_F4   1600000   // 50000*128/4
#define W_F4   4096      // 128*128/4
__global__ __launch_bounds__(256) void convert(const float* __restrict__ x,
                                               const float* __restrict__ W1,
                                               const float* __restrict__ W2,
                                               unsigned short* __restrict__ xbf,
                                               unsigned short* __restrict__ w1bf,
                                               unsigned short* __restrict__ w2bf,
                                               int* __restrict__ cnt)
{
    int gid    = blockIdx.x * 256 + threadIdx.x;
    int stride = gridDim.x * 256;
    if (gid < N_NODES) cnt[gid] = 0;         // stride (524288) covers 50000 once
    for (int i = gid; i < X_F4 + 2 * W_F4; i += stride) {
        float4 v; ush4* dst;
        if (i < X_F4)            { v = ((const float4*)x )[i];
                                   dst = (ush4*)xbf  + i; }
        else if (i < X_F4 + W_F4){ v = ((const float4*)W1)[i - X_F4];
                                   dst = (ush4*)w1bf + (i - X_F4); }
        else                     { v = ((const float4*)W2)[i - X_F4 - W_F4];
                                   dst = (ush4*)w2bf + (i - X_F4 - W_F4); }
        ush4 p; p[0] = f2bf(v.x); p[1] = f2bf(v.y); p[2] = f2bf(v.z); p[3] = f2bf(v.w);
        *dst = p;
    }
}

// ---------------------------------------------------------------------------
// LDS-free dual GEMM: out = x@W1^T (fp32), hbf = rowL2norm(x@W2^T) (bf16).
// Deg-normalization cancels under row L2-norm (positive scalar).
// 256 thr (4 waves) x 16 rows/wave = 64 rows/block, grid 782 -> no LDS cap,
// no barriers. A-frags read once from xbf; B-frags from 64KB L2-resident wbf.
// MFMA 16x16x32: A row=lane&15, k=(lane>>4)*8+j ; C/D col=lane&15,
// row=(lane>>4)*4+reg  [m89-verified layout]
// ---------------------------------------------------------------------------
__global__ __launch_bounds__(256) void gemm2(const unsigned short* __restrict__ xbf,
                                             const unsigned short* __restrict__ w1bf,
                                             const unsigned short* __restrict__ w2bf,
                                             float* __restrict__ out,
                                             unsigned short* __restrict__ hbf)
{
    const int t    = threadIdx.x;
    const int wave = t >> 6;
    const int lane = t & 63;
    const int g    = lane >> 4;      // k-group / row-quad group
    const int ln   = lane & 15;
    const int rowbase = blockIdx.x * 64 + wave * 16;

    // A fragments for this wave's 16 rows (row rowbase+ln), all K
    int arow = rowbase + ln;
    int arowc = (arow < N_NODES) ? arow : (N_NODES - 1);   // clamp (stores guarded)
    short8 afrag[4];
    #pragma unroll
    for (int ks = 0; ks < 4; ++ks)
        afrag[ks] = *(const short8*)&xbf[(size_t)arowc * D + ks * 32 + g * 8];

    f32x4 acc1[8], acc2[8];
    #pragma unroll
    for (int ct = 0; ct < 8; ++ct) {
        f32x4 a1 = {0.f, 0.f, 0.f, 0.f}, a2 = {0.f, 0.f, 0.f, 0.f};
        #pragma unroll
        for (int ks = 0; ks < 4; ++ks) {
            short8 b1 = *(const short8*)&w1bf[(ct * 16 + ln) * D + ks * 32 + g * 8];
            short8 b2 = *(const short8*)&w2bf[(ct * 16 + ln) * D + ks * 32 + g * 8];
            a1 = __builtin_amdgcn_mfma_f32_16x16x32_bf16(afrag[ks], b1, a1, 0, 0, 0);
            a2 = __builtin_amdgcn_mfma_f32_16x16x32_bf16(afrag[ks], b2, a2, 0, 0, 0);
        }
        acc1[ct] = a1; acc2[ct] = a2;
    }

    // fused row-L2-normalize of the W2 half (row = g*4+r, cols spread over ln)
    float ss[4] = {0.f, 0.f, 0.f, 0.f};
    #pragma unroll
    for (int ct = 0; ct < 8; ++ct)
        #pragma unroll
        for (int r = 0; r < 4; ++r)
            ss[r] = fmaf(acc2[ct][r], acc2[ct][r], ss[r]);
    #pragma unroll
    for (int r = 0; r < 4; ++r)
        #pragma unroll
        for (int o = 1; o < 16; o <<= 1)
            ss[r] += __shfl_xor(ss[r], o, 64);
    float scale[4];
    #pragma unroll
    for (int r = 0; r < 4; ++r)
        scale[r] = 1.0f / fmaxf(sqrtf(ss[r]), 1e-12f);

    #pragma unroll
    for (int r = 0; r < 4; ++r) {
        int grow = rowbase + g * 4 + r;
        if (grow < N_NODES) {
            #pragma unroll
            for (int ct = 0; ct < 8; ++ct) {
                out[(size_t)grow * D + ct * 16 + ln] = acc1[ct][r];
                hbf[(size_t)grow * D + ct * 16 + ln] = f2bf(acc2[ct][r] * scale[r]);
            }
        }
    }
}

// ---------------------------------------------------------------------------
// bucket build: one edge per thread, one index-atomic, 2B bucket entries
// (src < 50000 < 2^16) to halve dirty-line writeback traffic.
// ---------------------------------------------------------------------------
__global__ __launch_bounds__(256) void fill_buckets(const int* __restrict__ ei,
                                                    int* __restrict__ cnt,
                                                    unsigned short* __restrict__ bucket)
{
    int e = blockIdx.x * 256 + threadIdx.x;
    if (e >= N_EDGES) return;
    int s = ei[e];                 // src
    int d = ei[N_EDGES + e];       // dst
    int p = atomicAdd(&cnt[d], 1);
    if (p < CAP) bucket[d * CAP + p] = (unsigned short)s;
}

// ---------------------------------------------------------------------------
// per-dst gather-max over bf16 h rows, fused out += ; 8-deep ILP
// ---------------------------------------------------------------------------
__global__ __launch_bounds__(256) void gather_max(const unsigned short* __restrict__ hbf,
                                                  const int* __restrict__ cnt,
                                                  const unsigned short* __restrict__ bucket,
                                                  float* __restrict__ out)
{
    int wid  = (blockIdx.x * 256 + threadIdx.x) >> 6;
    int lane = threadIdx.x & 63;
    if (wid >= N_NODES) return;
    int deg = cnt[wid];
    deg = (deg > CAP) ? CAP : deg;
    if (deg == 0) return;              // empty segment contributes 0

    const uint32_t* h32 = (const uint32_t*)hbf;   // 64 uints (=128 bf16) per row
    int sl = (lane < deg) ? (int)bucket[wid * CAP + lane] : 0;

    float mx = -INFINITY, my = -INFINITY;         // cols 2*lane, 2*lane+1
    int j = 0;
    for (; j + 8 <= deg; j += 8) {
        uint32_t u[8];
        #pragma unroll
        for (int q = 0; q < 8; ++q) {
            int s = __shfl(sl, j + q, 64);
            u[q] = h32[(size_t)s * 64 + lane];
        }
        #pragma unroll
        for (int q = 0; q < 8; ++q) {
            mx = fmaxf(mx, __uint_as_float(u[q] << 16));
            my = fmaxf(my, __uint_as_float(u[q] & 0xFFFF0000u));
        }
    }
    for (; j < deg; ++j) {
        int s = __shfl(sl, j, 64);
        uint32_t u = h32[(size_t)s * 64 + lane];
        mx = fmaxf(mx, __uint_as_float(u << 16));
        my = fmaxf(my, __uint_as_float(u & 0xFFFF0000u));
    }

    float2* o2 = (float2*)out;
    float2 o = o2[(size_t)wid * 64 + lane];
    o.x += mx; o.y += my;
    o2[(size_t)wid * 64 + lane] = o;
}

extern "C" void kernel_launch(void* const* d_in, const int* in_sizes, int n_in,
                              void* d_out, int out_size, void* d_ws, size_t ws_size,
                              hipStream_t stream)
{
    const float* x  = (const float*)d_in[0];
    const float* W1 = (const float*)d_in[1];
    const float* W2 = (const float*)d_in[2];
    const int*   ei = (const int*)d_in[3];
    float* out = (float*)d_out;

    char* ws = (char*)d_ws;
    const size_t XBF = (size_t)N_NODES * D * 2;          // 12.8 MB
    unsigned short* xbf    = (unsigned short*)ws;
    unsigned short* hbf    = (unsigned short*)(ws + XBF);                 // 12.8 MB
    unsigned short* w1bf   = (unsigned short*)(ws + 2 * XBF);             // 32 KB
    unsigned short* w2bf   = (unsigned short*)(ws + 2 * XBF + 32768);     // 32 KB
    int*            cnt    = (int*)(ws + 2 * XBF + 65536);                // 200 KB
    unsigned short* bucket = (unsigned short*)(ws + 2 * XBF + 65536 + 200704); // 6.4 MB

    convert<<<2048, 256, 0, stream>>>(x, W1, W2, xbf, w1bf, w2bf, cnt);
    gemm2<<<(N_NODES + 63) / 64, 256, 0, stream>>>(xbf, w1bf, w2bf, out, hbf);
    fill_buckets<<<(N_EDGES + 255) / 256, 256, 0, stream>>>(ei, cnt, bucket);
    gather_max<<<(N_NODES * 64 + 255) / 256, 256, 0, stream>>>(hbf, cnt, bucket, out);
}

// Round 11
// 162.238 us; speedup vs baseline: 1.2377x; 1.2377x over previous
//
#include <hip/hip_runtime.h>
#include <stdint.h>

#define N_NODES 50000
#define N_EDGES 800000
#define D 128
#define CAP 64      // max in-degree supported; Poisson(16) -> P(>=64) ~ 1e-20
#define LDK 136     // padded LDS K-stride (bf16 elems): +8 -> 2-way bank alias (free)
#define NBLK 391    // ceil(50000/128)
#define NT_FILL (NBLK * 512)   // 200192 threads; x4 edges = 800768 >= N_EDGES

typedef __attribute__((ext_vector_type(8))) short short8;
typedef __attribute__((ext_vector_type(4))) float f32x4;
typedef __attribute__((ext_vector_type(4))) unsigned short ush4;

__device__ __forceinline__ unsigned short f2bf(float f) {   // RNE f32->bf16
    uint32_t u = __float_as_uint(f);
    u += 0x7FFFu + ((u >> 16) & 1u);
    return (unsigned short)(u >> 16);
}

// ---------------------------------------------------------------------------
// gemm_fill: out = x@W1^T (fp32), hbf = rowL2norm(x@W2^T) (bf16),
//            PLUS edge-bucket build overlapped with the MFMA phase.
// Deg-normalization cancels under row L2-norm (positive scalar).
// Atomic schedule: (src,dst) loaded at kernel start; atomicAdds issued right
// after __syncthreads (post-staging, so no vmcnt wait drains them); MFMA phase
// is LDS-only (lgkmcnt); atomic results consumed only in the epilogue ->
// ~50us of TCC atomic processing hides under ~45us of matrix work.
// MFMA 16x16x32: A row=lane&15, k=(lane>>4)*8+j ; C/D col=lane&15,
// row=(lane>>4)*4+reg  [m89-verified layout; r8-passed absmax 0.031]
// ---------------------------------------------------------------------------
__global__ __launch_bounds__(512) void gemm_fill(const float* __restrict__ x,
                                                 const float* __restrict__ W1,
                                                 const float* __restrict__ W2,
                                                 const int* __restrict__ ei,
                                                 float* __restrict__ out,
                                                 unsigned short* __restrict__ hbf,
                                                 int* __restrict__ cnt,
                                                 unsigned short* __restrict__ bucket)
{
    __shared__ unsigned short wsm[256][LDK];  // n 0..127 = W1 rows, 128..255 = W2
    __shared__ unsigned short xs[128][LDK];

    const int t    = threadIdx.x;
    const int row0 = blockIdx.x * 128;
    const int gid  = blockIdx.x * 512 + t;

    // ---- edge pairs: load early (cheap, completes during staging) ----
    int es[4], ed[4];
    #pragma unroll
    for (int k = 0; k < 4; ++k) {
        int e = gid + k * NT_FILL;
        bool v = (e < N_EDGES);
        es[k] = v ? ei[e] : 0;
        ed[k] = v ? ei[N_EDGES + e] : -1;
    }

    // ---- stage W1|W2 -> bf16 LDS: 256 rows x 32 float4 ----
    #pragma unroll
    for (int it = 0; it < 16; ++it) {
        int idx = it * 512 + t;
        int n = idx >> 5, c4 = idx & 31;
        const float* Wp = (n < 128) ? (W1 + (size_t)n * D) : (W2 + (size_t)(n - 128) * D);
        float4 v = *(const float4*)(Wp + c4 * 4);
        ush4 p; p[0] = f2bf(v.x); p[1] = f2bf(v.y); p[2] = f2bf(v.z); p[3] = f2bf(v.w);
        *(ush4*)&wsm[n][c4 * 4] = p;
    }
    // ---- stage x tile -> bf16 LDS: 128 rows x 32 float4 (zero-pad OOB) ----
    #pragma unroll
    for (int it = 0; it < 8; ++it) {
        int idx = it * 512 + t;
        int r = idx >> 5, c4 = idx & 31;
        int gr = row0 + r;
        float4 v = make_float4(0.f, 0.f, 0.f, 0.f);
        if (gr < N_NODES) v = *(const float4*)(x + (size_t)gr * D + c4 * 4);
        ush4 p; p[0] = f2bf(v.x); p[1] = f2bf(v.y); p[2] = f2bf(v.z); p[3] = f2bf(v.w);
        *(ush4*)&xs[r][c4 * 4] = p;
    }
    __syncthreads();

    // ---- issue index-atomics NOW; results not read until the epilogue ----
    int ep[4];
    #pragma unroll
    for (int k = 0; k < 4; ++k)
        ep[k] = (ed[k] >= 0) ? atomicAdd(&cnt[ed[k]], 1) : CAP;

    // ---- MFMA phase (LDS-only waits; atomics fly in the background) ----
    const int wave = t >> 6;
    const int lane = t & 63;
    const int g    = lane >> 4;
    const int ln   = lane & 15;

    short8 afrag[4];
    #pragma unroll
    for (int ks = 0; ks < 4; ++ks)
        afrag[ks] = *(const short8*)&xs[wave * 16 + ln][ks * 32 + g * 8];

    f32x4 acc1[8], acc2[8];
    #pragma unroll
    for (int ct = 0; ct < 8; ++ct) {
        f32x4 a1 = {0.f, 0.f, 0.f, 0.f}, a2 = {0.f, 0.f, 0.f, 0.f};
        #pragma unroll
        for (int ks = 0; ks < 4; ++ks) {
            short8 b1 = *(const short8*)&wsm[      ct * 16 + ln][ks * 32 + g * 8];
            short8 b2 = *(const short8*)&wsm[128 + ct * 16 + ln][ks * 32 + g * 8];
            a1 = __builtin_amdgcn_mfma_f32_16x16x32_bf16(afrag[ks], b1, a1, 0, 0, 0);
            a2 = __builtin_amdgcn_mfma_f32_16x16x32_bf16(afrag[ks], b2, a2, 0, 0, 0);
        }
        acc1[ct] = a1; acc2[ct] = a2;
    }

    // ---- fused row-L2-normalize of the W2 half ----
    float ss[4] = {0.f, 0.f, 0.f, 0.f};
    #pragma unroll
    for (int ct = 0; ct < 8; ++ct)
        #pragma unroll
        for (int r = 0; r < 4; ++r)
            ss[r] = fmaf(acc2[ct][r], acc2[ct][r], ss[r]);
    #pragma unroll
    for (int r = 0; r < 4; ++r)
        #pragma unroll
        for (int o = 1; o < 16; o <<= 1)
            ss[r] += __shfl_xor(ss[r], o, 64);
    float scale[4];
    #pragma unroll
    for (int r = 0; r < 4; ++r)
        scale[r] = 1.0f / fmaxf(sqrtf(ss[r]), 1e-12f);

    #pragma unroll
    for (int r = 0; r < 4; ++r) {
        int grow = row0 + wave * 16 + g * 4 + r;
        if (grow < N_NODES) {
            #pragma unroll
            for (int ct = 0; ct < 8; ++ct) {
                out[(size_t)grow * D + ct * 16 + ln] = acc1[ct][r];
                hbf[(size_t)grow * D + ct * 16 + ln] = f2bf(acc2[ct][r] * scale[r]);
            }
        }
    }

    // ---- epilogue: consume atomic results, write 2B bucket entries ----
    #pragma unroll
    for (int k = 0; k < 4; ++k)
        if (ed[k] >= 0 && ep[k] < CAP)
            bucket[ed[k] * CAP + ep[k]] = (unsigned short)es[k];
}

// ---------------------------------------------------------------------------
// per-dst gather-max over bf16 h rows, fused out += ; 8-deep ILP
// ---------------------------------------------------------------------------
__global__ __launch_bounds__(256) void gather_max(const unsigned short* __restrict__ hbf,
                                                  const int* __restrict__ cnt,
                                                  const unsigned short* __restrict__ bucket,
                                                  float* __restrict__ out)
{
    int wid  = (blockIdx.x * 256 + threadIdx.x) >> 6;
    int lane = threadIdx.x & 63;
    if (wid >= N_NODES) return;
    int deg = cnt[wid];
    deg = (deg > CAP) ? CAP : deg;
    if (deg == 0) return;              // empty segment contributes 0

    const uint32_t* h32 = (const uint32_t*)hbf;   // 64 uints (=128 bf16) per row
    int sl = (lane < deg) ? (int)bucket[wid * CAP + lane] : 0;

    float mx = -INFINITY, my = -INFINITY;         // cols 2*lane, 2*lane+1
    int j = 0;
    for (; j + 8 <= deg; j += 8) {
        uint32_t u[8];
        #pragma unroll
        for (int q = 0; q < 8; ++q) {
            int s = __shfl(sl, j + q, 64);
            u[q] = h32[(size_t)s * 64 + lane];
        }
        #pragma unroll
        for (int q = 0; q < 8; ++q) {
            mx = fmaxf(mx, __uint_as_float(u[q] << 16));
            my = fmaxf(my, __uint_as_float(u[q] & 0xFFFF0000u));
        }
    }
    for (; j < deg; ++j) {
        int s = __shfl(sl, j, 64);
        uint32_t u = h32[(size_t)s * 64 + lane];
        mx = fmaxf(mx, __uint_as_float(u << 16));
        my = fmaxf(my, __uint_as_float(u & 0xFFFF0000u));
    }

    float2* o2 = (float2*)out;
    float2 o = o2[(size_t)wid * 64 + lane];
    o.x += mx; o.y += my;
    o2[(size_t)wid * 64 + lane] = o;
}

extern "C" void kernel_launch(void* const* d_in, const int* in_sizes, int n_in,
                              void* d_out, int out_size, void* d_ws, size_t ws_size,
                              hipStream_t stream)
{
    const float* x  = (const float*)d_in[0];
    const float* W1 = (const float*)d_in[1];
    const float* W2 = (const float*)d_in[2];
    const int*   ei = (const int*)d_in[3];
    float* out = (float*)d_out;

    char* ws = (char*)d_ws;
    unsigned short* hbf    = (unsigned short*)ws;                          // 12.8 MB
    int*            cnt    = (int*)(ws + (size_t)N_NODES * D * 2);         // 200 KB
    unsigned short* bucket = (unsigned short*)(ws + (size_t)N_NODES * D * 2
                                                  + (size_t)N_NODES * 4);  // 6.4 MB

    hipMemsetAsync(cnt, 0, (size_t)N_NODES * 4, stream);
    gemm_fill<<<NBLK, 512, 0, stream>>>(x, W1, W2, ei, out, hbf, cnt, bucket);
    gather_max<<<(N_NODES * 64 + 255) / 256, 256, 0, stream>>>(hbf, cnt, bucket, out);
}